// Round 5
// baseline (159.645 us; speedup 1.0000x reference)
//
#include <hip/hip_runtime.h>
#include <math.h>

#define NW     10
#define DIM    1024
#define QDEPTH 16

typedef __attribute__((ext_vector_type(8))) _Float16 f16x8;
typedef __attribute__((ext_vector_type(4))) _Float16 f16x4;
typedef __attribute__((ext_vector_type(2))) _Float16 f16x2;
typedef __attribute__((ext_vector_type(4))) float    f32x4;

// ---------------- ws layout ----------------
// gates : @0        (160 gates * 8 floats = 5120 B)
// iperm : @8192     (16*1024*4 = 64 KB)  forward CNOT-block gather tables
// invs  : @81920    (8192*4 = 32 KB)
// Xh    : @1 MB     (8192*1024*2 = 16 MB)   f16 cast of x, row-major (B,K)
// B_il  : @17 MB    (2048*1024*2 = 4 MB)    f16, rows 2j=Re U[j,:], 2j+1=Im U[j,:]
// Ucol  : scratch in d_out (4 MB needed, d_out is 32 MB; fully overwritten by gemm)
#define WS_GATES 0
#define WS_IPERM 8192
#define WS_INVS  81920
#define WS_XH    (1u << 20)
#define WS_BIL   (17u << 20)

// padded LDS slot: breaks power-of-2 stride bank conflicts
#define SLOT(i) ((i) + ((i) >> 4))

__device__ inline void gate2(const float* __restrict__ g, float2& p0, float2& p1) {
    float m00r = g[0], m00i = g[1], m01r = g[2], m01i = g[3];
    float m10r = g[4], m10i = g[5], m11r = g[6], m11i = g[7];
    float n0x = m00r*p0.x - m00i*p0.y + m01r*p1.x - m01i*p1.y;
    float n0y = m00r*p0.y + m00i*p0.x + m01r*p1.y + m01i*p1.x;
    float n1x = m10r*p0.x - m10i*p0.y + m11r*p1.x - m11i*p1.y;
    float n1y = m10r*p0.y + m10i*p0.x + m11r*p1.y + m11i*p1.x;
    p0 = make_float2(n0x, n0y);
    p1 = make_float2(n1x, n1y);
}

__global__ __launch_bounds__(1024)
void prep_kernel(const float* __restrict__ w, float* __restrict__ gates,
                 int* __restrict__ iperm) {
    int t = threadIdx.x;
    const float PI = 3.14159265358979323846f;
    if (t < QDEPTH * NW) {
        // Rot(phi,theta,omega) = RZ(omega) RY(theta) RZ(phi); angles = tanh(w)*pi
        float phi   = tanhf(w[t*3 + 0]) * PI;
        float theta = tanhf(w[t*3 + 1]) * PI;
        float omega = tanhf(w[t*3 + 2]) * PI;
        float ch = cosf(theta * 0.5f), sh = sinf(theta * 0.5f);
        float ap = (phi + omega) * 0.5f;
        float am = (phi - omega) * 0.5f;
        float* g = gates + t * 8;
        g[0] =  cosf(ap) * ch;  g[1] = -sinf(ap) * ch;   // m00
        g[2] = -cosf(am) * sh;  g[3] = -sinf(am) * sh;   // m01
        g[4] =  cosf(am) * sh;  g[5] = -sinf(am) * sh;   // m10
        g[6] =  cosf(ap) * ch;  g[7] =  sinf(ap) * ch;   // m11
    }
    // Forward CNOT-block gather (round-1 verified): state'[v] = state[G_l(v)]
    int v = t;
    for (int l = 0; l < QDEPTH; ++l) {
        int r = (l % (NW - 1)) + 1;
        int u = v;
        for (int wq = NW - 1; wq >= 0; --wq) {
            int bc = 9 - wq;
            int bt = 9 - ((wq + r) % NW);
            u ^= ((u >> bc) & 1) << bt;
        }
        iperm[l * DIM + v] = u;
    }
}

// Column builder: block v simulates basis state e_v, writes column v of U
// contiguously: Ucol[v][2j] = Re U[j,v], Ucol[v][2j+1] = Im U[j,v].
__global__ __launch_bounds__(256)
void ubuild_kernel(const float* __restrict__ gates, const int* __restrict__ iperm,
                   _Float16* __restrict__ Ucol) {
    __shared__ float2 st[DIM + 64];
    const int v = blockIdx.x;
    const int t = threadIdx.x;

    #pragma unroll
    for (int k = 0; k < 4; ++k) {
        int i = t + k * 256;
        st[SLOT(i)] = make_float2(i == v ? 1.f : 0.f, 0.f);
    }
    __syncthreads();

    for (int l = 0; l < QDEPTH; ++l) {
        const float* gl = gates + l * NW * 8;
        #pragma unroll
        for (int pb = 4; pb >= 0; --pb) {
            const int b = 2 * pb;
            const float* gh = gl + (8 - b) * 8;     // gate on bit b+1 (wire 8-b)
            const float* gm = gl + (9 - b) * 8;     // gate on bit b   (wire 9-b)
            const int low = t & ((1 << b) - 1);
            const int i00 = ((t >> b) << (b + 2)) | low;
            const int i01 = i00 | (1 << b);
            const int i10 = i00 | (2 << b);
            const int i11 = i00 | (3 << b);
            float2 a00 = st[SLOT(i00)], a01 = st[SLOT(i01)];
            float2 a10 = st[SLOT(i10)], a11 = st[SLOT(i11)];
            gate2(gh, a00, a10);
            gate2(gh, a01, a11);
            gate2(gm, a00, a01);
            gate2(gm, a10, a11);
            st[SLOT(i00)] = a00; st[SLOT(i01)] = a01;
            st[SLOT(i10)] = a10; st[SLOT(i11)] = a11;
            __syncthreads();
        }
        const int* ip = iperm + l * DIM;
        int j0 = ip[t], j1 = ip[t + 256], j2 = ip[t + 512], j3 = ip[t + 768];
        float2 b0 = st[SLOT(j0)], b1 = st[SLOT(j1)];
        float2 b2 = st[SLOT(j2)], b3 = st[SLOT(j3)];
        __syncthreads();
        st[SLOT(t)]       = b0;
        st[SLOT(t + 256)] = b1;
        st[SLOT(t + 512)] = b2;
        st[SLOT(t + 768)] = b3;
        __syncthreads();
    }

    _Float16* col = Ucol + (size_t)v * 2048;
    #pragma unroll
    for (int k = 0; k < 4; ++k) {
        int i = t + k * 256;
        float2 a = st[SLOT(i)];
        f16x2 p;
        p[0] = (_Float16)a.x;
        p[1] = (_Float16)a.y;
        *(f16x2*)(col + 2 * i) = p;
    }
}

// Bil[n][k] = Ucol[k][n], n<2048, k<1024. LDS-tiled 64x64 transpose.
__global__ __launch_bounds__(256)
void transpose_kernel(const _Float16* __restrict__ Ucol, _Float16* __restrict__ Bil) {
    __shared__ _Float16 tile[64][72];
    const int bx = blockIdx.x;          // n-tile: 0..31
    const int by = blockIdx.y;          // k-tile: 0..15
    const int t  = threadIdx.x;
    const int r  = t >> 3;              // 0..31
    const int c8 = (t & 7) * 8;         // 0..56

    #pragma unroll
    for (int kk = 0; kk < 64; kk += 32) {
        *(f16x8*)&tile[kk + r][c8] =
            *(const f16x8*)(Ucol + (size_t)(by * 64 + kk + r) * 2048 + bx * 64 + c8);
    }
    __syncthreads();
    #pragma unroll
    for (int nn = 0; nn < 64; nn += 32) {
        f16x8 o;
        #pragma unroll
        for (int j = 0; j < 8; ++j) o[j] = tile[c8 + j][nn + r];
        *(f16x8*)(Bil + (size_t)(bx * 64 + nn + r) * 1024 + by * 64 + c8) = o;
    }
}

// Per-row sumsq + f16 cast. One wave per batch row.
__global__ __launch_bounds__(64)
void normcast_kernel(const float* __restrict__ x, _Float16* __restrict__ Xh,
                     float* __restrict__ invs) {
    const int b = blockIdx.x;
    const int l = threadIdx.x;
    const float4* xr = (const float4*)(x + (size_t)b * DIM);
    float4 v[4];
    float ss = 0.f;
    #pragma unroll
    for (int c = 0; c < 4; ++c) {
        v[c] = xr[l + c * 64];
        ss += v[c].x*v[c].x + v[c].y*v[c].y + v[c].z*v[c].z + v[c].w*v[c].w;
    }
    #pragma unroll
    for (int o = 32; o >= 1; o >>= 1) ss += __shfl_down(ss, o, 64);
    ss = __shfl(ss, 0, 64);
    if (l == 0) invs[b] = 1024.0f / ss;
    f16x4* xo = (f16x4*)(Xh + (size_t)b * DIM);
    #pragma unroll
    for (int c = 0; c < 4; ++c) {
        f16x4 h;
        h[0] = (_Float16)v[c].x; h[1] = (_Float16)v[c].y;
        h[2] = (_Float16)v[c].z; h[3] = (_Float16)v[c].w;
        xo[l + c * 64] = h;
    }
}

// C[b,n] = sum_k Xh[b,k] * Bil[n,k];  out[b, n>>1] = clip(invs[b]*(c_even^2+c_odd^2), 0, 1)
// M=8192, N=2048, K=1024. 128x128 tile, BK=32, 4 waves (2x2), 4x4 16x16x32 frags.
// Double-buffered LDS + prefetch-before-compute (T3-minimum): one barrier/K-step,
// vmcnt drain hidden under the 16 MFMAs. XCD-aware block swizzle (T1).
#define BM 128
#define BN 128
#define BK 32
#define KSTEPS 32

__global__ __launch_bounds__(256)
void gemm_kernel(const _Float16* __restrict__ A, const _Float16* __restrict__ B,
                 const float* __restrict__ invs, float* __restrict__ out) {
    __shared__ _Float16 As[2][BM * BK];   // 2 x 8 KB
    __shared__ _Float16 Bs[2][BN * BK];   // 2 x 8 KB
    const int t    = threadIdx.x;
    const int lane = t & 63;
    const int wid  = t >> 6;
    const int wm = wid >> 1, wn = wid & 1;

    // T1: XCD-aware swizzle. nwg=1024, 1024%8==0 -> simple bijective form.
    // bid%8 = XCD; give each XCD 128 contiguous tiles (8 full m-panels).
    const int bid = blockIdx.x;
    const int swz = (bid & 7) * 128 + (bid >> 3);
    const int m0 = (swz >> 4) * BM;       // 64 m-tiles
    const int n0 = (swz & 15) * BN;       // 16 n-tiles

    const int srow   = t >> 2;
    const int schunk = (t & 3) * 8;
    const _Float16* Ag = A + (size_t)(m0 + srow) * 1024 + schunk;
    const _Float16* Bg = B + (size_t)(n0 + srow) * 1024 + schunk;

    f32x4 acc[4][4];
    const f32x4 zero = {0.f, 0.f, 0.f, 0.f};
    #pragma unroll
    for (int i = 0; i < 4; ++i)
        #pragma unroll
        for (int j = 0; j < 4; ++j) acc[i][j] = zero;

    const int fr = lane & 15;
    const int fk = (lane >> 4) * 8;

    #define STAGE(buf, kt)                                                          \
        do {                                                                        \
            __builtin_amdgcn_global_load_lds(                                       \
                (const __attribute__((address_space(1))) void*)(Ag + (kt)),         \
                (__attribute__((address_space(3))) void*)(&As[buf][t * 8]), 16, 0, 0); \
            __builtin_amdgcn_global_load_lds(                                       \
                (const __attribute__((address_space(1))) void*)(Ag + (kt) + 64 * 1024), \
                (__attribute__((address_space(3))) void*)(&As[buf][2048 + t * 8]), 16, 0, 0); \
            __builtin_amdgcn_global_load_lds(                                       \
                (const __attribute__((address_space(1))) void*)(Bg + (kt)),         \
                (__attribute__((address_space(3))) void*)(&Bs[buf][t * 8]), 16, 0, 0); \
            __builtin_amdgcn_global_load_lds(                                       \
                (const __attribute__((address_space(1))) void*)(Bg + (kt) + 64 * 1024), \
                (__attribute__((address_space(3))) void*)(&Bs[buf][2048 + t * 8]), 16, 0, 0); \
        } while (0)

    int cur = 0;
    STAGE(0, 0);
    __syncthreads();   // drains vmcnt(0): buffer 0 ready

    for (int s = 0; s < KSTEPS; ++s) {
        if (s + 1 < KSTEPS) STAGE(cur ^ 1, (s + 1) * BK);  // prefetch next tile

        f16x8 af[4], bf[4];
        #pragma unroll
        for (int mf = 0; mf < 4; ++mf)
            af[mf] = *(const f16x8*)(&As[cur][(wm * 64 + mf * 16 + fr) * BK + fk]);
        #pragma unroll
        for (int nf = 0; nf < 4; ++nf)
            bf[nf] = *(const f16x8*)(&Bs[cur][(wn * 64 + nf * 16 + fr) * BK + fk]);
        #pragma unroll
        for (int mf = 0; mf < 4; ++mf)
            #pragma unroll
            for (int nf = 0; nf < 4; ++nf)
                acc[mf][nf] = __builtin_amdgcn_mfma_f32_16x16x32_f16(
                    af[mf], bf[nf], acc[mf][nf], 0, 0, 0);

        // __syncthreads emits s_waitcnt vmcnt(0) lgkmcnt(0) before s_barrier:
        // prefetch landed, all reads of As[cur]/Bs[cur] complete -> safe to flip.
        __syncthreads();
        cur ^= 1;
    }
    #undef STAGE

    const int colf = lane & 15;
    const int rowf = (lane >> 4) * 4;
    #pragma unroll
    for (int mf = 0; mf < 4; ++mf) {
        #pragma unroll
        for (int nf = 0; nf < 4; ++nf) {
            const int n = n0 + wn * 64 + nf * 16 + colf;
            #pragma unroll
            for (int r = 0; r < 4; ++r) {
                const int row = m0 + wm * 64 + mf * 16 + rowf + r;
                float vv = acc[mf][nf][r];
                float sq = vv * vv;
                float other = __shfl_xor(sq, 1, 64);
                if (!(lane & 1)) {
                    float p = fminf((sq + other) * invs[row], 1.0f);
                    out[(size_t)row * DIM + (n >> 1)] = p;
                }
            }
        }
    }
}

extern "C" void kernel_launch(void* const* d_in, const int* in_sizes, int n_in,
                              void* d_out, int out_size, void* d_ws, size_t ws_size,
                              hipStream_t stream) {
    const float* x = (const float*)d_in[0];     // (8192,1,32,32) fp32
    const float* w = (const float*)d_in[1];     // (16,10,3) fp32
    float* out = (float*)d_out;                 // (8192,1,32,32) fp32

    char* ws = (char*)d_ws;
    float*     gates = (float*)(ws + WS_GATES);
    int*       iperm = (int*)(ws + WS_IPERM);
    float*     invs  = (float*)(ws + WS_INVS);
    _Float16*  Xh    = (_Float16*)(ws + WS_XH);
    _Float16*  Bil   = (_Float16*)(ws + WS_BIL);
    // Ucol scratch lives in d_out (4 MB of its 32 MB); consumed by transpose
    // before gemm overwrites every element of d_out.
    _Float16*  Ucol  = (_Float16*)d_out;

    prep_kernel<<<1, 1024, 0, stream>>>(w, gates, iperm);
    normcast_kernel<<<8192, 64, 0, stream>>>(x, Xh, invs);
    ubuild_kernel<<<1024, 256, 0, stream>>>(gates, iperm, Ucol);
    transpose_kernel<<<dim3(32, 16), 256, 0, stream>>>(Ucol, Bil);
    gemm_kernel<<<1024, 256, 0, stream>>>(Xh, Bil, invs, out);
}

// Round 6
// 146.970 us; speedup vs baseline: 1.0862x; 1.0862x over previous
//
#include <hip/hip_runtime.h>
#include <math.h>

#define NW     10
#define DIM    1024
#define QDEPTH 16

typedef __attribute__((ext_vector_type(8))) _Float16 f16x8;
typedef __attribute__((ext_vector_type(4))) _Float16 f16x4;
typedef __attribute__((ext_vector_type(2))) _Float16 f16x2;
typedef __attribute__((ext_vector_type(4))) float    f32x4;

// ---------------- ws layout ----------------
#define WS_GATES 0
#define WS_IPERM 8192
#define WS_INVS  81920
#define WS_XH    (1u << 20)
#define WS_BIL   (17u << 20)

// padded LDS slot for ubuild
#define SLOT(i) ((i) + ((i) >> 4))

__device__ inline void gate2(const float* __restrict__ g, float2& p0, float2& p1) {
    float m00r = g[0], m00i = g[1], m01r = g[2], m01i = g[3];
    float m10r = g[4], m10i = g[5], m11r = g[6], m11i = g[7];
    float n0x = m00r*p0.x - m00i*p0.y + m01r*p1.x - m01i*p1.y;
    float n0y = m00r*p0.y + m00i*p0.x + m01r*p1.y + m01i*p1.x;
    float n1x = m10r*p0.x - m10i*p0.y + m11r*p1.x - m11i*p1.y;
    float n1y = m10r*p0.y + m10i*p0.x + m11r*p1.y + m11i*p1.x;
    p0 = make_float2(n0x, n0y);
    p1 = make_float2(n1x, n1y);
}

__global__ __launch_bounds__(1024)
void prep_kernel(const float* __restrict__ w, float* __restrict__ gates,
                 int* __restrict__ iperm) {
    int t = threadIdx.x;
    const float PI = 3.14159265358979323846f;
    if (t < QDEPTH * NW) {
        float phi   = tanhf(w[t*3 + 0]) * PI;
        float theta = tanhf(w[t*3 + 1]) * PI;
        float omega = tanhf(w[t*3 + 2]) * PI;
        float ch = cosf(theta * 0.5f), sh = sinf(theta * 0.5f);
        float ap = (phi + omega) * 0.5f;
        float am = (phi - omega) * 0.5f;
        float* g = gates + t * 8;
        g[0] =  cosf(ap) * ch;  g[1] = -sinf(ap) * ch;   // m00
        g[2] = -cosf(am) * sh;  g[3] = -sinf(am) * sh;   // m01
        g[4] =  cosf(am) * sh;  g[5] = -sinf(am) * sh;   // m10
        g[6] =  cosf(ap) * ch;  g[7] =  sinf(ap) * ch;   // m11
    }
    int v = t;
    for (int l = 0; l < QDEPTH; ++l) {
        int r = (l % (NW - 1)) + 1;
        int u = v;
        for (int wq = NW - 1; wq >= 0; --wq) {
            int bc = 9 - wq;
            int bt = 9 - ((wq + r) % NW);
            u ^= ((u >> bc) & 1) << bt;
        }
        iperm[l * DIM + v] = u;
    }
}

// Column builder: block v simulates basis state e_v, writes column v of U
// contiguously: Ucol[v][2j] = Re U[j,v], Ucol[v][2j+1] = Im U[j,v].
__global__ __launch_bounds__(256)
void ubuild_kernel(const float* __restrict__ gates, const int* __restrict__ iperm,
                   _Float16* __restrict__ Ucol) {
    __shared__ float2 st[DIM + 64];
    const int v = blockIdx.x;
    const int t = threadIdx.x;

    #pragma unroll
    for (int k = 0; k < 4; ++k) {
        int i = t + k * 256;
        st[SLOT(i)] = make_float2(i == v ? 1.f : 0.f, 0.f);
    }
    __syncthreads();

    for (int l = 0; l < QDEPTH; ++l) {
        const float* gl = gates + l * NW * 8;
        #pragma unroll
        for (int pb = 4; pb >= 0; --pb) {
            const int b = 2 * pb;
            const float* gh = gl + (8 - b) * 8;     // gate on bit b+1 (wire 8-b)
            const float* gm = gl + (9 - b) * 8;     // gate on bit b   (wire 9-b)
            const int low = t & ((1 << b) - 1);
            const int i00 = ((t >> b) << (b + 2)) | low;
            const int i01 = i00 | (1 << b);
            const int i10 = i00 | (2 << b);
            const int i11 = i00 | (3 << b);
            float2 a00 = st[SLOT(i00)], a01 = st[SLOT(i01)];
            float2 a10 = st[SLOT(i10)], a11 = st[SLOT(i11)];
            gate2(gh, a00, a10);
            gate2(gh, a01, a11);
            gate2(gm, a00, a01);
            gate2(gm, a10, a11);
            st[SLOT(i00)] = a00; st[SLOT(i01)] = a01;
            st[SLOT(i10)] = a10; st[SLOT(i11)] = a11;
            __syncthreads();
        }
        const int* ip = iperm + l * DIM;
        int j0 = ip[t], j1 = ip[t + 256], j2 = ip[t + 512], j3 = ip[t + 768];
        float2 b0 = st[SLOT(j0)], b1 = st[SLOT(j1)];
        float2 b2 = st[SLOT(j2)], b3 = st[SLOT(j3)];
        __syncthreads();
        st[SLOT(t)]       = b0;
        st[SLOT(t + 256)] = b1;
        st[SLOT(t + 512)] = b2;
        st[SLOT(t + 768)] = b3;
        __syncthreads();
    }

    _Float16* col = Ucol + (size_t)v * 2048;
    #pragma unroll
    for (int k = 0; k < 4; ++k) {
        int i = t + k * 256;
        float2 a = st[SLOT(i)];
        f16x2 p;
        p[0] = (_Float16)a.x;
        p[1] = (_Float16)a.y;
        *(f16x2*)(col + 2 * i) = p;
    }
}

// Bil[n][k] = Ucol[k][n], n<2048, k<1024. LDS-tiled 64x64 transpose.
__global__ __launch_bounds__(256)
void transpose_kernel(const _Float16* __restrict__ Ucol, _Float16* __restrict__ Bil) {
    __shared__ _Float16 tile[64][72];
    const int bx = blockIdx.x;          // n-tile: 0..31
    const int by = blockIdx.y;          // k-tile: 0..15
    const int t  = threadIdx.x;
    const int r  = t >> 3;              // 0..31
    const int c8 = (t & 7) * 8;         // 0..56

    #pragma unroll
    for (int kk = 0; kk < 64; kk += 32) {
        *(f16x8*)&tile[kk + r][c8] =
            *(const f16x8*)(Ucol + (size_t)(by * 64 + kk + r) * 2048 + bx * 64 + c8);
    }
    __syncthreads();
    #pragma unroll
    for (int nn = 0; nn < 64; nn += 32) {
        f16x8 o;
        #pragma unroll
        for (int j = 0; j < 8; ++j) o[j] = tile[c8 + j][nn + r];
        *(f16x8*)(Bil + (size_t)(bx * 64 + nn + r) * 1024 + by * 64 + c8) = o;
    }
}

// Per-row sumsq + f16 cast. One wave per batch row.
__global__ __launch_bounds__(64)
void normcast_kernel(const float* __restrict__ x, _Float16* __restrict__ Xh,
                     float* __restrict__ invs) {
    const int b = blockIdx.x;
    const int l = threadIdx.x;
    const float4* xr = (const float4*)(x + (size_t)b * DIM);
    float4 v[4];
    float ss = 0.f;
    #pragma unroll
    for (int c = 0; c < 4; ++c) {
        v[c] = xr[l + c * 64];
        ss += v[c].x*v[c].x + v[c].y*v[c].y + v[c].z*v[c].z + v[c].w*v[c].w;
    }
    #pragma unroll
    for (int o = 32; o >= 1; o >>= 1) ss += __shfl_down(ss, o, 64);
    ss = __shfl(ss, 0, 64);
    if (l == 0) invs[b] = 1024.0f / ss;
    f16x4* xo = (f16x4*)(Xh + (size_t)b * DIM);
    #pragma unroll
    for (int c = 0; c < 4; ++c) {
        f16x4 h;
        h[0] = (_Float16)v[c].x; h[1] = (_Float16)v[c].y;
        h[2] = (_Float16)v[c].z; h[3] = (_Float16)v[c].w;
        xo[l + c * 64] = h;
    }
}

// ---------------- GEMM: 256x256 tile, BK=32, 8 waves (2Mx4N), 3-buffer
// counted-vmcnt pipeline (T4), T2 chunk-XOR swizzle, T5 setprio, T1 XCD map.
// C[b,n] = sum_k Xh[b,k]*Bil[n,k]; out[b,n>>1] = clip(invs[b]*(ce^2+co^2),0,1)
#define GBM 256
#define GBN 256
#define GBK 32
#define GKS 32     // K / GBK

__global__ __launch_bounds__(512, 2)
void gemm_kernel(const _Float16* __restrict__ A, const _Float16* __restrict__ B,
                 const float* __restrict__ invs, float* __restrict__ out) {
    __shared__ _Float16 As[3][GBM * GBK];   // 3 x 16 KB
    __shared__ _Float16 Bs[3][GBN * GBK];   // 3 x 16 KB  (96 KB total)
    const int t    = threadIdx.x;
    const int lane = t & 63;
    const int wid  = t >> 6;      // 0..7
    const int wm   = wid >> 2;    // 0..1 : M-half (128 rows)
    const int wn   = wid & 3;     // 0..3 : N-quarter (64 cols)

    // T1: XCD x gets m-panels 4x..4x+3, all 8 n-panels (A 2MB/XCD; B via L3)
    const int bid   = blockIdx.x;          // 256 blocks
    const int local = bid >> 3;            // 0..31
    const int m0 = ((bid & 7) * 4 + (local & 3)) * GBM;
    const int n0 = (local >> 2) * GBN;

    // staging: thread t covers LDS elems [t*8, t*8+8) and [4096+t*8, ...)
    // LDS is linear; global source pre-swizzled: chunk c stored at pos c^((r>>1)&3)
    const int sr  = t >> 2;                       // row 0..127 (and +128)
    const int gc  = ((t & 3) ^ ((sr >> 1) & 3)) * 8;  // same for row sr+128
    const _Float16* Ag0 = A + (size_t)(m0 + sr) * 1024 + gc;
    const _Float16* Ag1 = A + (size_t)(m0 + 128 + sr) * 1024 + gc;
    const _Float16* Bg0 = B + (size_t)(n0 + sr) * 1024 + gc;
    const _Float16* Bg1 = B + (size_t)(n0 + 128 + sr) * 1024 + gc;

    #define STAGE(buf, kt)                                                           \
        do {                                                                         \
            __builtin_amdgcn_global_load_lds(                                        \
                (const __attribute__((address_space(1))) void*)(Ag0 + (kt)),         \
                (__attribute__((address_space(3))) void*)(&As[buf][t * 8]), 16, 0, 0); \
            __builtin_amdgcn_global_load_lds(                                        \
                (const __attribute__((address_space(1))) void*)(Ag1 + (kt)),         \
                (__attribute__((address_space(3))) void*)(&As[buf][4096 + t * 8]), 16, 0, 0); \
            __builtin_amdgcn_global_load_lds(                                        \
                (const __attribute__((address_space(1))) void*)(Bg0 + (kt)),         \
                (__attribute__((address_space(3))) void*)(&Bs[buf][t * 8]), 16, 0, 0); \
            __builtin_amdgcn_global_load_lds(                                        \
                (const __attribute__((address_space(1))) void*)(Bg1 + (kt)),         \
                (__attribute__((address_space(3))) void*)(&Bs[buf][4096 + t * 8]), 16, 0, 0); \
        } while (0)

    f32x4 acc[8][4];
    const f32x4 zero = {0.f, 0.f, 0.f, 0.f};
    #pragma unroll
    for (int i = 0; i < 8; ++i)
        #pragma unroll
        for (int j = 0; j < 4; ++j) acc[i][j] = zero;

    const int fr  = lane & 15;
    const int ch  = lane >> 4;            // which 8-elem k-chunk this lane reads
    const int sel = (fr >> 1) & 3;        // row-derived swizzle (wm*128, mf*16 are %4==0 in r>>1)
    const int cof = ((ch ^ sel) << 3);    // swizzled chunk offset in elems

    // prologue: tiles 0 and 1 in flight; wait tile 0 (4 younger loads remain)
    STAGE(0, 0);
    STAGE(1, GBK);
    asm volatile("s_waitcnt vmcnt(4)" ::: "memory");
    __builtin_amdgcn_s_barrier();
    __builtin_amdgcn_sched_barrier(0);

    int cur = 0;
    for (int s = 0; s < GKS; ++s) {
        int n2 = cur + 2; if (n2 >= 3) n2 -= 3;
        if (s + 2 < GKS) STAGE(n2, (s + 2) * GBK);   // tile s+2 -> buf (s+2)%3

        const _Float16* Ab = As[cur];
        const _Float16* Bb = Bs[cur];
        f16x8 af[8], bf[4];
        #pragma unroll
        for (int mf = 0; mf < 8; ++mf)
            af[mf] = *(const f16x8*)(Ab + (wm * 128 + mf * 16 + fr) * GBK + cof);
        #pragma unroll
        for (int nf = 0; nf < 4; ++nf)
            bf[nf] = *(const f16x8*)(Bb + (wn * 64 + nf * 16 + fr) * GBK + cof);

        __builtin_amdgcn_s_setprio(1);
        #pragma unroll
        for (int mf = 0; mf < 8; ++mf)
            #pragma unroll
            for (int nf = 0; nf < 4; ++nf)
                acc[mf][nf] = __builtin_amdgcn_mfma_f32_16x16x32_f16(
                    af[mf], bf[nf], acc[mf][nf], 0, 0, 0);
        __builtin_amdgcn_s_setprio(0);

        if (s + 1 < GKS) {
            // wait only tile s+1's loads; tile s+2's 4 stay in flight (never vmcnt(0)
            // mid-loop). Barrier => ALL waves' tile-s+1 loads landed; sched_barrier
            // pins ds_reads of the next iter below this point.
            if (s + 2 < GKS) asm volatile("s_waitcnt vmcnt(4)" ::: "memory");
            else             asm volatile("s_waitcnt vmcnt(0)" ::: "memory");
            __builtin_amdgcn_s_barrier();
            __builtin_amdgcn_sched_barrier(0);
        }
        int c1 = cur + 1; cur = (c1 == 3) ? 0 : c1;
    }
    #undef STAGE

    // epilogue: C row = m0+wm*128+mf*16+(lane>>4)*4+r ; col = n0+wn*64+nf*16+(lane&15)
    const int colf = lane & 15;
    const int rowf = (lane >> 4) * 4;
    #pragma unroll
    for (int mf = 0; mf < 8; ++mf) {
        #pragma unroll
        for (int nf = 0; nf < 4; ++nf) {
            const int n = n0 + wn * 64 + nf * 16 + colf;
            #pragma unroll
            for (int r = 0; r < 4; ++r) {
                const int row = m0 + wm * 128 + mf * 16 + rowf + r;
                float vv = acc[mf][nf][r];
                float sq = vv * vv;
                float other = __shfl_xor(sq, 1, 64);
                if (!(lane & 1)) {
                    float p = fminf((sq + other) * invs[row], 1.0f);
                    out[(size_t)row * DIM + (n >> 1)] = p;
                }
            }
        }
    }
}

extern "C" void kernel_launch(void* const* d_in, const int* in_sizes, int n_in,
                              void* d_out, int out_size, void* d_ws, size_t ws_size,
                              hipStream_t stream) {
    const float* x = (const float*)d_in[0];     // (8192,1,32,32) fp32
    const float* w = (const float*)d_in[1];     // (16,10,3) fp32
    float* out = (float*)d_out;                 // (8192,1,32,32) fp32

    char* ws = (char*)d_ws;
    float*     gates = (float*)(ws + WS_GATES);
    int*       iperm = (int*)(ws + WS_IPERM);
    float*     invs  = (float*)(ws + WS_INVS);
    _Float16*  Xh    = (_Float16*)(ws + WS_XH);
    _Float16*  Bil   = (_Float16*)(ws + WS_BIL);
    // Ucol scratch lives in d_out (4 MB of its 32 MB); consumed by transpose
    // before gemm overwrites every element of d_out.
    _Float16*  Ucol  = (_Float16*)d_out;

    prep_kernel<<<1, 1024, 0, stream>>>(w, gates, iperm);
    normcast_kernel<<<8192, 64, 0, stream>>>(x, Xh, invs);
    ubuild_kernel<<<1024, 256, 0, stream>>>(gates, iperm, Ucol);
    transpose_kernel<<<dim3(32, 16), 256, 0, stream>>>(Ucol, Bil);
    gemm_kernel<<<256, 512, 0, stream>>>(Xh, Bil, invs, out);
}

// Round 7
// 140.722 us; speedup vs baseline: 1.1345x; 1.0444x over previous
//
#include <hip/hip_runtime.h>
#include <math.h>

#define NW     10
#define DIM    1024
#define QDEPTH 16

typedef __attribute__((ext_vector_type(8))) _Float16 f16x8;
typedef __attribute__((ext_vector_type(4))) _Float16 f16x4;
typedef __attribute__((ext_vector_type(2))) _Float16 f16x2;
typedef __attribute__((ext_vector_type(4))) float    f32x4;

// ---------------- ws layout ----------------
#define WS_GATES 0
#define WS_IPERM 8192
#define WS_INVS  81920
#define WS_XH    (1u << 20)
#define WS_BIL   (17u << 20)

// padded LDS slot for ubuild
#define SLOT(i) ((i) + ((i) >> 4))

__device__ inline void gate2(const float* __restrict__ g, float2& p0, float2& p1) {
    float m00r = g[0], m00i = g[1], m01r = g[2], m01i = g[3];
    float m10r = g[4], m10i = g[5], m11r = g[6], m11i = g[7];
    float n0x = m00r*p0.x - m00i*p0.y + m01r*p1.x - m01i*p1.y;
    float n0y = m00r*p0.y + m00i*p0.x + m01r*p1.y + m01i*p1.x;
    float n1x = m10r*p0.x - m10i*p0.y + m11r*p1.x - m11i*p1.y;
    float n1y = m10r*p0.y + m10i*p0.x + m11r*p1.y + m11i*p1.x;
    p0 = make_float2(n0x, n0y);
    p1 = make_float2(n1x, n1y);
}

__global__ __launch_bounds__(1024)
void prep_kernel(const float* __restrict__ w, float* __restrict__ gates,
                 int* __restrict__ iperm) {
    int t = threadIdx.x;
    const float PI = 3.14159265358979323846f;
    if (t < QDEPTH * NW) {
        float phi   = tanhf(w[t*3 + 0]) * PI;
        float theta = tanhf(w[t*3 + 1]) * PI;
        float omega = tanhf(w[t*3 + 2]) * PI;
        float ch = cosf(theta * 0.5f), sh = sinf(theta * 0.5f);
        float ap = (phi + omega) * 0.5f;
        float am = (phi - omega) * 0.5f;
        float* g = gates + t * 8;
        g[0] =  cosf(ap) * ch;  g[1] = -sinf(ap) * ch;   // m00
        g[2] = -cosf(am) * sh;  g[3] = -sinf(am) * sh;   // m01
        g[4] =  cosf(am) * sh;  g[5] = -sinf(am) * sh;   // m10
        g[6] =  cosf(ap) * ch;  g[7] =  sinf(ap) * ch;   // m11
    }
    int v = t;
    for (int l = 0; l < QDEPTH; ++l) {
        int r = (l % (NW - 1)) + 1;
        int u = v;
        for (int wq = NW - 1; wq >= 0; --wq) {
            int bc = 9 - wq;
            int bt = 9 - ((wq + r) % NW);
            u ^= ((u >> bc) & 1) << bt;
        }
        iperm[l * DIM + v] = u;
    }
}

// Column builder: block v simulates basis state e_v, writes column v of U
// contiguously: Ucol[v][2j] = Re U[j,v], Ucol[v][2j+1] = Im U[j,v].
__global__ __launch_bounds__(256)
void ubuild_kernel(const float* __restrict__ gates, const int* __restrict__ iperm,
                   _Float16* __restrict__ Ucol) {
    __shared__ float2 st[DIM + 64];
    const int v = blockIdx.x;
    const int t = threadIdx.x;

    #pragma unroll
    for (int k = 0; k < 4; ++k) {
        int i = t + k * 256;
        st[SLOT(i)] = make_float2(i == v ? 1.f : 0.f, 0.f);
    }
    __syncthreads();

    for (int l = 0; l < QDEPTH; ++l) {
        const float* gl = gates + l * NW * 8;
        #pragma unroll
        for (int pb = 4; pb >= 0; --pb) {
            const int b = 2 * pb;
            const float* gh = gl + (8 - b) * 8;     // gate on bit b+1 (wire 8-b)
            const float* gm = gl + (9 - b) * 8;     // gate on bit b   (wire 9-b)
            const int low = t & ((1 << b) - 1);
            const int i00 = ((t >> b) << (b + 2)) | low;
            const int i01 = i00 | (1 << b);
            const int i10 = i00 | (2 << b);
            const int i11 = i00 | (3 << b);
            float2 a00 = st[SLOT(i00)], a01 = st[SLOT(i01)];
            float2 a10 = st[SLOT(i10)], a11 = st[SLOT(i11)];
            gate2(gh, a00, a10);
            gate2(gh, a01, a11);
            gate2(gm, a00, a01);
            gate2(gm, a10, a11);
            st[SLOT(i00)] = a00; st[SLOT(i01)] = a01;
            st[SLOT(i10)] = a10; st[SLOT(i11)] = a11;
            __syncthreads();
        }
        const int* ip = iperm + l * DIM;
        int j0 = ip[t], j1 = ip[t + 256], j2 = ip[t + 512], j3 = ip[t + 768];
        float2 b0 = st[SLOT(j0)], b1 = st[SLOT(j1)];
        float2 b2 = st[SLOT(j2)], b3 = st[SLOT(j3)];
        __syncthreads();
        st[SLOT(t)]       = b0;
        st[SLOT(t + 256)] = b1;
        st[SLOT(t + 512)] = b2;
        st[SLOT(t + 768)] = b3;
        __syncthreads();
    }

    _Float16* col = Ucol + (size_t)v * 2048;
    #pragma unroll
    for (int k = 0; k < 4; ++k) {
        int i = t + k * 256;
        float2 a = st[SLOT(i)];
        f16x2 p;
        p[0] = (_Float16)a.x;
        p[1] = (_Float16)a.y;
        *(f16x2*)(col + 2 * i) = p;
    }
}

// Bil[n][k] = Ucol[k][n], n<2048, k<1024. LDS-tiled 64x64 transpose.
__global__ __launch_bounds__(256)
void transpose_kernel(const _Float16* __restrict__ Ucol, _Float16* __restrict__ Bil) {
    __shared__ _Float16 tile[64][72];
    const int bx = blockIdx.x;          // n-tile: 0..31
    const int by = blockIdx.y;          // k-tile: 0..15
    const int t  = threadIdx.x;
    const int r  = t >> 3;              // 0..31
    const int c8 = (t & 7) * 8;         // 0..56

    #pragma unroll
    for (int kk = 0; kk < 64; kk += 32) {
        *(f16x8*)&tile[kk + r][c8] =
            *(const f16x8*)(Ucol + (size_t)(by * 64 + kk + r) * 2048 + bx * 64 + c8);
    }
    __syncthreads();
    #pragma unroll
    for (int nn = 0; nn < 64; nn += 32) {
        f16x8 o;
        #pragma unroll
        for (int j = 0; j < 8; ++j) o[j] = tile[c8 + j][nn + r];
        *(f16x8*)(Bil + (size_t)(bx * 64 + nn + r) * 1024 + by * 64 + c8) = o;
    }
}

// Per-row sumsq + f16 cast. One wave per batch row.
__global__ __launch_bounds__(64)
void normcast_kernel(const float* __restrict__ x, _Float16* __restrict__ Xh,
                     float* __restrict__ invs) {
    const int b = blockIdx.x;
    const int l = threadIdx.x;
    const float4* xr = (const float4*)(x + (size_t)b * DIM);
    float4 v[4];
    float ss = 0.f;
    #pragma unroll
    for (int c = 0; c < 4; ++c) {
        v[c] = xr[l + c * 64];
        ss += v[c].x*v[c].x + v[c].y*v[c].y + v[c].z*v[c].z + v[c].w*v[c].w;
    }
    #pragma unroll
    for (int o = 32; o >= 1; o >>= 1) ss += __shfl_down(ss, o, 64);
    ss = __shfl(ss, 0, 64);
    if (l == 0) invs[b] = 1024.0f / ss;
    f16x4* xo = (f16x4*)(Xh + (size_t)b * DIM);
    #pragma unroll
    for (int c = 0; c < 4; ++c) {
        f16x4 h;
        h[0] = (_Float16)v[c].x; h[1] = (_Float16)v[c].y;
        h[2] = (_Float16)v[c].z; h[3] = (_Float16)v[c].w;
        xo[l + c * 64] = h;
    }
}

// ---------------- GEMM: 256x256 tile, BK=64, 8-phase-style schedule ----------
// 8 waves (2M x 4N), per-wave output 128x64. LDS = 2 dbuf x 2 half x 2 ops
// x 16 KB = 128 KB. Per K-tile: 4 phases, each {ds_read subtile | stage one
// half-tile | barrier | lgkm(0) | 16 MFMA | barrier}. Stage skewed one phase:
// boundary wait is vmcnt(2), never 0 mid-loop (T4). T2 chunk-XOR swizzle
// (global-source pre-swizzle + swizzled ds_read). T5 setprio. T1 XCD map.
#define GBK 64
#define NKT 16     // 1024 / 64

// f16x8 frag read from a half-slot: hrow in [0,128), logical 16B-chunk c in [0,8)
__device__ __forceinline__ f16x8 ldsfrag(const _Float16* base, int hrow, int c) {
    return *(const f16x8*)(base + hrow * 64 + ((c ^ (hrow & 7)) << 3));
}

__global__ __launch_bounds__(512, 2)
void gemm_kernel(const _Float16* __restrict__ A, const _Float16* __restrict__ B,
                 const float* __restrict__ invs, float* __restrict__ out) {
    __shared__ _Float16 As[2][2][8192];   // [buf][M-half][128 rows x 64 k], 64 KB
    __shared__ _Float16 Bs[2][2][8192];   // [buf][N-half][...], 64 KB
    const int t    = threadIdx.x;
    const int lane = t & 63;
    const int wid  = t >> 6;      // 0..7
    const int wm   = wid >> 2;    // 0..1 : M-half (128 rows)
    const int wn   = wid & 3;     // 0..3 : N-quarter (64 cols)

    // T1: XCD x gets m-panels 4x..4x+3, all 8 n-panels
    const int bid   = blockIdx.x;          // 256 blocks
    const int local = bid >> 3;            // 0..31
    const int m0 = ((bid & 7) * 4 + (local & 3)) * 256;
    const int n0 = (local >> 2) * 256;

    const _Float16* Ag0 = A + (size_t)m0 * 1024;          // A-half0 (rows m0..+127)
    const _Float16* Ag1 = A + (size_t)(m0 + 128) * 1024;  // A-half1
    const _Float16* Bg0 = B + (size_t)n0 * 1024;
    const _Float16* Bg1 = B + (size_t)(n0 + 128) * 1024;

    // staging: thread t covers dest 16B-chunks d=t and d=512+t of a half-tile
    // (16 KB). dest is LINEAR (rule #21); source chunk is pre-swizzled:
    // gc = (d&7) ^ ((d>>3)&7). (d>>3)&7 is identical for d and d+512.
    const int srow = t >> 3;                       // 0..63 (and +64)
    const int sgc  = ((t & 7) ^ (srow & 7)) * 8;   // swizzled source chunk, elems
    #define STAGE_HALF(dst, gbase, kt)                                              \
        do {                                                                        \
            __builtin_amdgcn_global_load_lds(                                       \
                (const __attribute__((address_space(1))) void*)                     \
                    ((gbase) + (size_t)srow * 1024 + (kt) * 64 + sgc),              \
                (__attribute__((address_space(3))) void*)((dst) + t * 8), 16, 0, 0);\
            __builtin_amdgcn_global_load_lds(                                       \
                (const __attribute__((address_space(1))) void*)                     \
                    ((gbase) + (size_t)(64 + srow) * 1024 + (kt) * 64 + sgc),       \
                (__attribute__((address_space(3))) void*)((dst) + 4096 + t * 8),    \
                16, 0, 0);                                                          \
        } while (0)

    f32x4 acc[8][4];
    const f32x4 zero = {0.f, 0.f, 0.f, 0.f};
    #pragma unroll
    for (int i = 0; i < 8; ++i)
        #pragma unroll
        for (int j = 0; j < 4; ++j) acc[i][j] = zero;

    const int fr = lane & 15;       // frag row within 16
    const int ch = lane >> 4;       // 16B chunk within 32-k sub-tile

    // ---- prologue: tile 0 fully + A-half0 of tile 1; wait tile 0 only ----
    STAGE_HALF(&As[0][0][0], Ag0, 0);
    STAGE_HALF(&As[0][1][0], Ag1, 0);
    STAGE_HALF(&Bs[0][0][0], Bg0, 0);
    STAGE_HALF(&Bs[0][1][0], Bg1, 0);
    STAGE_HALF(&As[1][0][0], Ag0, 1);
    asm volatile("s_waitcnt vmcnt(2)" ::: "memory");
    __builtin_amdgcn_s_barrier();
    __builtin_amdgcn_sched_barrier(0);

    for (int tk = 0; tk < NKT; ++tk) {
        const int buf = tk & 1, nbuf = buf ^ 1;
        const _Float16* Ab = &As[buf][wm][0];
        const _Float16* Bb = &Bs[buf][wn >> 1][0];
        const int bro = (wn & 1) * 64;            // B hrow offset within half

        f16x8 afl[4][2], afh[4][2], bfa[2][2], bfb[2][2];

        // ---- phase 0: read afl + bfa; stage A-half1(t+1) ----
        #pragma unroll
        for (int m = 0; m < 4; ++m)
            #pragma unroll
            for (int ks = 0; ks < 2; ++ks)
                afl[m][ks] = ldsfrag(Ab, m * 16 + fr, ks * 4 + ch);
        #pragma unroll
        for (int n = 0; n < 2; ++n)
            #pragma unroll
            for (int ks = 0; ks < 2; ++ks)
                bfa[n][ks] = ldsfrag(Bb, bro + n * 16 + fr, ks * 4 + ch);
        if (tk + 1 < NKT) STAGE_HALF(&As[nbuf][1][0], Ag1, tk + 1);
        __builtin_amdgcn_s_barrier();
        asm volatile("s_waitcnt lgkmcnt(0)" ::: "memory");
        __builtin_amdgcn_sched_barrier(0);
        __builtin_amdgcn_s_setprio(1);
        #pragma unroll
        for (int m = 0; m < 4; ++m)
            #pragma unroll
            for (int n = 0; n < 2; ++n)
                #pragma unroll
                for (int ks = 0; ks < 2; ++ks)
                    acc[m][n] = __builtin_amdgcn_mfma_f32_16x16x32_f16(
                        afl[m][ks], bfa[n][ks], acc[m][n], 0, 0, 0);
        __builtin_amdgcn_s_setprio(0);
        __builtin_amdgcn_s_barrier();
        __builtin_amdgcn_sched_barrier(0);

        // ---- phase 1: read bfb; stage B-half0(t+1) ----
        #pragma unroll
        for (int n = 0; n < 2; ++n)
            #pragma unroll
            for (int ks = 0; ks < 2; ++ks)
                bfb[n][ks] = ldsfrag(Bb, bro + (2 + n) * 16 + fr, ks * 4 + ch);
        if (tk + 1 < NKT) STAGE_HALF(&Bs[nbuf][0][0], Bg0, tk + 1);
        __builtin_amdgcn_s_barrier();
        asm volatile("s_waitcnt lgkmcnt(0)" ::: "memory");
        __builtin_amdgcn_sched_barrier(0);
        __builtin_amdgcn_s_setprio(1);
        #pragma unroll
        for (int m = 0; m < 4; ++m)
            #pragma unroll
            for (int n = 0; n < 2; ++n)
                #pragma unroll
                for (int ks = 0; ks < 2; ++ks)
                    acc[m][2 + n] = __builtin_amdgcn_mfma_f32_16x16x32_f16(
                        afl[m][ks], bfb[n][ks], acc[m][2 + n], 0, 0, 0);
        __builtin_amdgcn_s_setprio(0);
        __builtin_amdgcn_s_barrier();
        __builtin_amdgcn_sched_barrier(0);

        // ---- phase 2: read afh; stage B-half1(t+1) ----
        #pragma unroll
        for (int m = 0; m < 4; ++m)
            #pragma unroll
            for (int ks = 0; ks < 2; ++ks)
                afh[m][ks] = ldsfrag(Ab, 64 + m * 16 + fr, ks * 4 + ch);
        if (tk + 1 < NKT) STAGE_HALF(&Bs[nbuf][1][0], Bg1, tk + 1);
        __builtin_amdgcn_s_barrier();
        asm volatile("s_waitcnt lgkmcnt(0)" ::: "memory");
        __builtin_amdgcn_sched_barrier(0);
        __builtin_amdgcn_s_setprio(1);
        #pragma unroll
        for (int m = 0; m < 4; ++m)
            #pragma unroll
            for (int n = 0; n < 2; ++n)
                #pragma unroll
                for (int ks = 0; ks < 2; ++ks)
                    acc[4 + m][n] = __builtin_amdgcn_mfma_f32_16x16x32_f16(
                        afh[m][ks], bfa[n][ks], acc[4 + m][n], 0, 0, 0);
        __builtin_amdgcn_s_setprio(0);
        __builtin_amdgcn_s_barrier();
        __builtin_amdgcn_sched_barrier(0);

        // ---- phase 3: stage A-half0(t+2) into As[buf][0] (dead since p2) ----
        if (tk + 2 < NKT) STAGE_HALF(&As[buf][0][0], Ag0, tk + 2);
        __builtin_amdgcn_s_barrier();
        asm volatile("s_waitcnt lgkmcnt(0)" ::: "memory");
        __builtin_amdgcn_sched_barrier(0);
        __builtin_amdgcn_s_setprio(1);
        #pragma unroll
        for (int m = 0; m < 4; ++m)
            #pragma unroll
            for (int n = 0; n < 2; ++n)
                #pragma unroll
                for (int ks = 0; ks < 2; ++ks)
                    acc[4 + m][2 + n] = __builtin_amdgcn_mfma_f32_16x16x32_f16(
                        afh[m][ks], bfb[n][ks], acc[4 + m][2 + n], 0, 0, 0);
        __builtin_amdgcn_s_setprio(0);
        // boundary: tile t+1 ready when only A0(t+2)'s 2 loads remain in flight
        if (tk + 1 < NKT) {
            if (tk + 2 < NKT) asm volatile("s_waitcnt vmcnt(2)" ::: "memory");
            else              asm volatile("s_waitcnt vmcnt(0)" ::: "memory");
            __builtin_amdgcn_s_barrier();
            __builtin_amdgcn_sched_barrier(0);
        }
    }
    #undef STAGE_HALF

    // epilogue: C row = m0+wm*128+mf*16+(lane>>4)*4+r ; col = n0+wn*64+nf*16+(lane&15)
    const int colf = lane & 15;
    const int rowf = (lane >> 4) * 4;
    #pragma unroll
    for (int mf = 0; mf < 8; ++mf) {
        #pragma unroll
        for (int nf = 0; nf < 4; ++nf) {
            const int n = n0 + wn * 64 + nf * 16 + colf;
            #pragma unroll
            for (int r = 0; r < 4; ++r) {
                const int row = m0 + wm * 128 + mf * 16 + rowf + r;
                float vv = acc[mf][nf][r];
                float sq = vv * vv;
                float other = __shfl_xor(sq, 1, 64);
                if (!(lane & 1)) {
                    float p = fminf((sq + other) * invs[row], 1.0f);
                    out[(size_t)row * DIM + (n >> 1)] = p;
                }
            }
        }
    }
}

extern "C" void kernel_launch(void* const* d_in, const int* in_sizes, int n_in,
                              void* d_out, int out_size, void* d_ws, size_t ws_size,
                              hipStream_t stream) {
    const float* x = (const float*)d_in[0];     // (8192,1,32,32) fp32
    const float* w = (const float*)d_in[1];     // (16,10,3) fp32
    float* out = (float*)d_out;                 // (8192,1,32,32) fp32

    char* ws = (char*)d_ws;
    float*     gates = (float*)(ws + WS_GATES);
    int*       iperm = (int*)(ws + WS_IPERM);
    float*     invs  = (float*)(ws + WS_INVS);
    _Float16*  Xh    = (_Float16*)(ws + WS_XH);
    _Float16*  Bil   = (_Float16*)(ws + WS_BIL);
    // Ucol scratch lives in d_out (4 MB of its 32 MB); consumed by transpose
    // before gemm overwrites every element of d_out.
    _Float16*  Ucol  = (_Float16*)d_out;

    prep_kernel<<<1, 1024, 0, stream>>>(w, gates, iperm);
    normcast_kernel<<<8192, 64, 0, stream>>>(x, Xh, invs);
    ubuild_kernel<<<1024, 256, 0, stream>>>(gates, iperm, Ucol);
    transpose_kernel<<<dim3(32, 16), 256, 0, stream>>>(Ucol, Bil);
    gemm_kernel<<<256, 512, 0, stream>>>(Xh, Bil, invs, out);
}

// Round 8
// 135.852 us; speedup vs baseline: 1.1751x; 1.0358x over previous
//
#include <hip/hip_runtime.h>
#include <math.h>

#define NW     10
#define DIM    1024
#define QDEPTH 16

typedef __attribute__((ext_vector_type(8))) _Float16 f16x8;
typedef __attribute__((ext_vector_type(4))) _Float16 f16x4;
typedef __attribute__((ext_vector_type(2))) _Float16 f16x2;
typedef __attribute__((ext_vector_type(4))) float    f32x4;

// ---------------- ws layout ----------------
#define WS_GATES 0
#define WS_IPERM 8192
#define WS_INVS  81920
#define WS_XH    (1u << 20)
#define WS_BIL   (17u << 20)

// padded LDS slot for ubuild
#define SLOT(i) ((i) + ((i) >> 4))

__device__ inline void gate2(const float* __restrict__ g, float2& p0, float2& p1) {
    float m00r = g[0], m00i = g[1], m01r = g[2], m01i = g[3];
    float m10r = g[4], m10i = g[5], m11r = g[6], m11i = g[7];
    float n0x = m00r*p0.x - m00i*p0.y + m01r*p1.x - m01i*p1.y;
    float n0y = m00r*p0.y + m00i*p0.x + m01r*p1.y + m01i*p1.x;
    float n1x = m10r*p0.x - m10i*p0.y + m11r*p1.x - m11i*p1.y;
    float n1y = m10r*p0.y + m10i*p0.x + m11r*p1.y + m11i*p1.x;
    p0 = make_float2(n0x, n0y);
    p1 = make_float2(n1x, n1y);
}

__global__ __launch_bounds__(1024)
void prep_kernel(const float* __restrict__ w, float* __restrict__ gates,
                 int* __restrict__ iperm) {
    int t = threadIdx.x;
    const float PI = 3.14159265358979323846f;
    if (t < QDEPTH * NW) {
        float phi   = tanhf(w[t*3 + 0]) * PI;
        float theta = tanhf(w[t*3 + 1]) * PI;
        float omega = tanhf(w[t*3 + 2]) * PI;
        float ch = cosf(theta * 0.5f), sh = sinf(theta * 0.5f);
        float ap = (phi + omega) * 0.5f;
        float am = (phi - omega) * 0.5f;
        float* g = gates + t * 8;
        g[0] =  cosf(ap) * ch;  g[1] = -sinf(ap) * ch;   // m00
        g[2] = -cosf(am) * sh;  g[3] = -sinf(am) * sh;   // m01
        g[4] =  cosf(am) * sh;  g[5] = -sinf(am) * sh;   // m10
        g[6] =  cosf(ap) * ch;  g[7] =  sinf(ap) * ch;   // m11
    }
    int v = t;
    for (int l = 0; l < QDEPTH; ++l) {
        int r = (l % (NW - 1)) + 1;
        int u = v;
        for (int wq = NW - 1; wq >= 0; --wq) {
            int bc = 9 - wq;
            int bt = 9 - ((wq + r) % NW);
            u ^= ((u >> bc) & 1) << bt;
        }
        iperm[l * DIM + v] = u;
    }
}

// Column builder: block v simulates basis state e_v, writes column v of U
// contiguously. Hoisted slot addressing; perm P_{l-1} fused into the b=8
// gate pass read (gather), P_15 fused into the output write.
__global__ __launch_bounds__(256)
void ubuild_kernel(const float* __restrict__ gates, const int* __restrict__ iperm,
                   _Float16* __restrict__ Ucol) {
    __shared__ float2 st[DIM + 64];
    const int v = blockIdx.x;
    const int t = threadIdx.x;

    // ---- hoisted layer-invariant slot indices (rule #20: unrolled, static idx) ----
    int s4[4];                 // canonical slots of the b=8 quad {t + k*256}
    #pragma unroll
    for (int k = 0; k < 4; ++k) s4[k] = SLOT(t + k * 256);
    int sq[4][4];              // quad slots for passes b = 0,2,4,6 (pp = b/2)
    #pragma unroll
    for (int pp = 0; pp < 4; ++pp) {
        const int b = 2 * pp;
        const int low = t & ((1 << b) - 1);
        const int i00 = ((t >> b) << (b + 2)) | low;
        sq[pp][0] = SLOT(i00);
        sq[pp][1] = SLOT(i00 | (1 << b));
        sq[pp][2] = SLOT(i00 | (2 << b));
        sq[pp][3] = SLOT(i00 | (3 << b));
    }

    // init: amp i at canonical slot (s4 over all t covers all 1024 slots)
    #pragma unroll
    for (int k = 0; k < 4; ++k) {
        int i = t + k * 256;
        st[s4[k]] = make_float2(i == v ? 1.f : 0.f, 0.f);
    }
    __syncthreads();

    for (int l = 0; l < QDEPTH; ++l) {
        const float* gl = gates + l * NW * 8;

        // ---- pass b=8 (wires 0,1) with fused gather of perm l-1 ----
        float2 a00, a01, a10, a11;
        if (l == 0) {
            a00 = st[s4[0]]; a01 = st[s4[1]]; a10 = st[s4[2]]; a11 = st[s4[3]];
        } else {
            const int* ipm = iperm + (l - 1) * DIM;
            int g0 = ipm[t], g1 = ipm[t + 256], g2 = ipm[t + 512], g3 = ipm[t + 768];
            a00 = st[SLOT(g0)]; a01 = st[SLOT(g1)];
            a10 = st[SLOT(g2)]; a11 = st[SLOT(g3)];
        }
        gate2(gl + 0, a00, a10);   // wire 0 (bit 9): pairs (a00,a10),(a01,a11)
        gate2(gl + 0, a01, a11);
        gate2(gl + 8, a00, a01);   // wire 1 (bit 8): pairs (a00,a01),(a10,a11)
        gate2(gl + 8, a10, a11);
        if (l) __syncthreads();    // gather slots owned by other threads: drain
                                   // all reads before canonical writes (l==0
                                   // reads are thread-exclusive -> no hazard)
        st[s4[0]] = a00; st[s4[1]] = a01; st[s4[2]] = a10; st[s4[3]] = a11;
        __syncthreads();

        // ---- passes b = 6,4,2,0: thread-exclusive quads ----
        #pragma unroll
        for (int pp = 3; pp >= 0; --pp) {
            const int b = 2 * pp;
            const float* gh = gl + (8 - b) * 8;   // gate on bit b+1 (wire 8-b)
            const float* gm = gl + (9 - b) * 8;   // gate on bit b   (wire 9-b)
            float2 c00 = st[sq[pp][0]], c01 = st[sq[pp][1]];
            float2 c10 = st[sq[pp][2]], c11 = st[sq[pp][3]];
            gate2(gh, c00, c10);
            gate2(gh, c01, c11);
            gate2(gm, c00, c01);
            gate2(gm, c10, c11);
            st[sq[pp][0]] = c00; st[sq[pp][1]] = c01;
            st[sq[pp][2]] = c10; st[sq[pp][3]] = c11;
            __syncthreads();
        }
    }

    // ---- output with fused final perm: col[i] = st[SLOT(G_15(i))] ----
    const int* ipl = iperm + (QDEPTH - 1) * DIM;
    _Float16* col = Ucol + (size_t)v * 2048;
    #pragma unroll
    for (int k = 0; k < 4; ++k) {
        int i = t + k * 256;
        int g = ipl[i];
        float2 a = st[SLOT(g)];
        f16x2 p;
        p[0] = (_Float16)a.x;
        p[1] = (_Float16)a.y;
        *(f16x2*)(col + 2 * i) = p;
    }
}

// Bil[n][k] = Ucol[k][n], n<2048, k<1024. LDS-tiled 64x64 transpose.
__global__ __launch_bounds__(256)
void transpose_kernel(const _Float16* __restrict__ Ucol, _Float16* __restrict__ Bil) {
    __shared__ _Float16 tile[64][72];
    const int bx = blockIdx.x;          // n-tile: 0..31
    const int by = blockIdx.y;          // k-tile: 0..15
    const int t  = threadIdx.x;
    const int r  = t >> 3;              // 0..31
    const int c8 = (t & 7) * 8;         // 0..56

    #pragma unroll
    for (int kk = 0; kk < 64; kk += 32) {
        *(f16x8*)&tile[kk + r][c8] =
            *(const f16x8*)(Ucol + (size_t)(by * 64 + kk + r) * 2048 + bx * 64 + c8);
    }
    __syncthreads();
    #pragma unroll
    for (int nn = 0; nn < 64; nn += 32) {
        f16x8 o;
        #pragma unroll
        for (int j = 0; j < 8; ++j) o[j] = tile[c8 + j][nn + r];
        *(f16x8*)(Bil + (size_t)(bx * 64 + nn + r) * 1024 + by * 64 + c8) = o;
    }
}

// Per-row sumsq + f16 cast. One wave per batch row.
__global__ __launch_bounds__(64)
void normcast_kernel(const float* __restrict__ x, _Float16* __restrict__ Xh,
                     float* __restrict__ invs) {
    const int b = blockIdx.x;
    const int l = threadIdx.x;
    const float4* xr = (const float4*)(x + (size_t)b * DIM);
    float4 v[4];
    float ss = 0.f;
    #pragma unroll
    for (int c = 0; c < 4; ++c) {
        v[c] = xr[l + c * 64];
        ss += v[c].x*v[c].x + v[c].y*v[c].y + v[c].z*v[c].z + v[c].w*v[c].w;
    }
    #pragma unroll
    for (int o = 32; o >= 1; o >>= 1) ss += __shfl_down(ss, o, 64);
    ss = __shfl(ss, 0, 64);
    if (l == 0) invs[b] = 1024.0f / ss;
    f16x4* xo = (f16x4*)(Xh + (size_t)b * DIM);
    #pragma unroll
    for (int c = 0; c < 4; ++c) {
        f16x4 h;
        h[0] = (_Float16)v[c].x; h[1] = (_Float16)v[c].y;
        h[2] = (_Float16)v[c].z; h[3] = (_Float16)v[c].w;
        xo[l + c * 64] = h;
    }
}

// ---------------- GEMM: 256x256 tile, BK=64, 8-phase-style schedule ----------
// (unchanged from round 7 - verified)
#define GBK 64
#define NKT 16     // 1024 / 64

__device__ __forceinline__ f16x8 ldsfrag(const _Float16* base, int hrow, int c) {
    return *(const f16x8*)(base + hrow * 64 + ((c ^ (hrow & 7)) << 3));
}

__global__ __launch_bounds__(512, 2)
void gemm_kernel(const _Float16* __restrict__ A, const _Float16* __restrict__ B,
                 const float* __restrict__ invs, float* __restrict__ out) {
    __shared__ _Float16 As[2][2][8192];   // [buf][M-half][128 rows x 64 k], 64 KB
    __shared__ _Float16 Bs[2][2][8192];   // [buf][N-half][...], 64 KB
    const int t    = threadIdx.x;
    const int lane = t & 63;
    const int wid  = t >> 6;      // 0..7
    const int wm   = wid >> 2;    // 0..1 : M-half (128 rows)
    const int wn   = wid & 3;     // 0..3 : N-quarter (64 cols)

    // T1: XCD x gets m-panels 4x..4x+3, all 8 n-panels
    const int bid   = blockIdx.x;          // 256 blocks
    const int local = bid >> 3;            // 0..31
    const int m0 = ((bid & 7) * 4 + (local & 3)) * 256;
    const int n0 = (local >> 2) * 256;

    const _Float16* Ag0 = A + (size_t)m0 * 1024;          // A-half0 (rows m0..+127)
    const _Float16* Ag1 = A + (size_t)(m0 + 128) * 1024;  // A-half1
    const _Float16* Bg0 = B + (size_t)n0 * 1024;
    const _Float16* Bg1 = B + (size_t)(n0 + 128) * 1024;

    const int srow = t >> 3;                       // 0..63 (and +64)
    const int sgc  = ((t & 7) ^ (srow & 7)) * 8;   // swizzled source chunk, elems
    #define STAGE_HALF(dst, gbase, kt)                                              \
        do {                                                                        \
            __builtin_amdgcn_global_load_lds(                                       \
                (const __attribute__((address_space(1))) void*)                     \
                    ((gbase) + (size_t)srow * 1024 + (kt) * 64 + sgc),              \
                (__attribute__((address_space(3))) void*)((dst) + t * 8), 16, 0, 0);\
            __builtin_amdgcn_global_load_lds(                                       \
                (const __attribute__((address_space(1))) void*)                     \
                    ((gbase) + (size_t)(64 + srow) * 1024 + (kt) * 64 + sgc),       \
                (__attribute__((address_space(3))) void*)((dst) + 4096 + t * 8),    \
                16, 0, 0);                                                          \
        } while (0)

    f32x4 acc[8][4];
    const f32x4 zero = {0.f, 0.f, 0.f, 0.f};
    #pragma unroll
    for (int i = 0; i < 8; ++i)
        #pragma unroll
        for (int j = 0; j < 4; ++j) acc[i][j] = zero;

    const int fr = lane & 15;       // frag row within 16
    const int ch = lane >> 4;       // 16B chunk within 32-k sub-tile

    // ---- prologue: tile 0 fully + A-half0 of tile 1; wait tile 0 only ----
    STAGE_HALF(&As[0][0][0], Ag0, 0);
    STAGE_HALF(&As[0][1][0], Ag1, 0);
    STAGE_HALF(&Bs[0][0][0], Bg0, 0);
    STAGE_HALF(&Bs[0][1][0], Bg1, 0);
    STAGE_HALF(&As[1][0][0], Ag0, 1);
    asm volatile("s_waitcnt vmcnt(2)" ::: "memory");
    __builtin_amdgcn_s_barrier();
    __builtin_amdgcn_sched_barrier(0);

    for (int tk = 0; tk < NKT; ++tk) {
        const int buf = tk & 1, nbuf = buf ^ 1;
        const _Float16* Ab = &As[buf][wm][0];
        const _Float16* Bb = &Bs[buf][wn >> 1][0];
        const int bro = (wn & 1) * 64;            // B hrow offset within half

        f16x8 afl[4][2], afh[4][2], bfa[2][2], bfb[2][2];

        // ---- phase 0: read afl + bfa; stage A-half1(t+1) ----
        #pragma unroll
        for (int m = 0; m < 4; ++m)
            #pragma unroll
            for (int ks = 0; ks < 2; ++ks)
                afl[m][ks] = ldsfrag(Ab, m * 16 + fr, ks * 4 + ch);
        #pragma unroll
        for (int n = 0; n < 2; ++n)
            #pragma unroll
            for (int ks = 0; ks < 2; ++ks)
                bfa[n][ks] = ldsfrag(Bb, bro + n * 16 + fr, ks * 4 + ch);
        if (tk + 1 < NKT) STAGE_HALF(&As[nbuf][1][0], Ag1, tk + 1);
        __builtin_amdgcn_s_barrier();
        asm volatile("s_waitcnt lgkmcnt(0)" ::: "memory");
        __builtin_amdgcn_sched_barrier(0);
        __builtin_amdgcn_s_setprio(1);
        #pragma unroll
        for (int m = 0; m < 4; ++m)
            #pragma unroll
            for (int n = 0; n < 2; ++n)
                #pragma unroll
                for (int ks = 0; ks < 2; ++ks)
                    acc[m][n] = __builtin_amdgcn_mfma_f32_16x16x32_f16(
                        afl[m][ks], bfa[n][ks], acc[m][n], 0, 0, 0);
        __builtin_amdgcn_s_setprio(0);
        __builtin_amdgcn_s_barrier();
        __builtin_amdgcn_sched_barrier(0);

        // ---- phase 1: read bfb; stage B-half0(t+1) ----
        #pragma unroll
        for (int n = 0; n < 2; ++n)
            #pragma unroll
            for (int ks = 0; ks < 2; ++ks)
                bfb[n][ks] = ldsfrag(Bb, bro + (2 + n) * 16 + fr, ks * 4 + ch);
        if (tk + 1 < NKT) STAGE_HALF(&Bs[nbuf][0][0], Bg0, tk + 1);
        __builtin_amdgcn_s_barrier();
        asm volatile("s_waitcnt lgkmcnt(0)" ::: "memory");
        __builtin_amdgcn_sched_barrier(0);
        __builtin_amdgcn_s_setprio(1);
        #pragma unroll
        for (int m = 0; m < 4; ++m)
            #pragma unroll
            for (int n = 0; n < 2; ++n)
                #pragma unroll
                for (int ks = 0; ks < 2; ++ks)
                    acc[m][2 + n] = __builtin_amdgcn_mfma_f32_16x16x32_f16(
                        afl[m][ks], bfb[n][ks], acc[m][2 + n], 0, 0, 0);
        __builtin_amdgcn_s_setprio(0);
        __builtin_amdgcn_s_barrier();
        __builtin_amdgcn_sched_barrier(0);

        // ---- phase 2: read afh; stage B-half1(t+1) ----
        #pragma unroll
        for (int m = 0; m < 4; ++m)
            #pragma unroll
            for (int ks = 0; ks < 2; ++ks)
                afh[m][ks] = ldsfrag(Ab, 64 + m * 16 + fr, ks * 4 + ch);
        if (tk + 1 < NKT) STAGE_HALF(&Bs[nbuf][1][0], Bg1, tk + 1);
        __builtin_amdgcn_s_barrier();
        asm volatile("s_waitcnt lgkmcnt(0)" ::: "memory");
        __builtin_amdgcn_sched_barrier(0);
        __builtin_amdgcn_s_setprio(1);
        #pragma unroll
        for (int m = 0; m < 4; ++m)
            #pragma unroll
            for (int n = 0; n < 2; ++n)
                #pragma unroll
                for (int ks = 0; ks < 2; ++ks)
                    acc[4 + m][n] = __builtin_amdgcn_mfma_f32_16x16x32_f16(
                        afh[m][ks], bfa[n][ks], acc[4 + m][n], 0, 0, 0);
        __builtin_amdgcn_s_setprio(0);
        __builtin_amdgcn_s_barrier();
        __builtin_amdgcn_sched_barrier(0);

        // ---- phase 3: stage A-half0(t+2) into As[buf][0] (dead since p2) ----
        if (tk + 2 < NKT) STAGE_HALF(&As[buf][0][0], Ag0, tk + 2);
        __builtin_amdgcn_s_barrier();
        asm volatile("s_waitcnt lgkmcnt(0)" ::: "memory");
        __builtin_amdgcn_sched_barrier(0);
        __builtin_amdgcn_s_setprio(1);
        #pragma unroll
        for (int m = 0; m < 4; ++m)
            #pragma unroll
            for (int n = 0; n < 2; ++n)
                #pragma unroll
                for (int ks = 0; ks < 2; ++ks)
                    acc[4 + m][2 + n] = __builtin_amdgcn_mfma_f32_16x16x32_f16(
                        afh[m][ks], bfb[n][ks], acc[4 + m][2 + n], 0, 0, 0);
        __builtin_amdgcn_s_setprio(0);
        // boundary: tile t+1 ready when only A0(t+2)'s 2 loads remain in flight
        if (tk + 1 < NKT) {
            if (tk + 2 < NKT) asm volatile("s_waitcnt vmcnt(2)" ::: "memory");
            else              asm volatile("s_waitcnt vmcnt(0)" ::: "memory");
            __builtin_amdgcn_s_barrier();
            __builtin_amdgcn_sched_barrier(0);
        }
    }
    #undef STAGE_HALF

    // epilogue: C row = m0+wm*128+mf*16+(lane>>4)*4+r ; col = n0+wn*64+nf*16+(lane&15)
    const int colf = lane & 15;
    const int rowf = (lane >> 4) * 4;
    #pragma unroll
    for (int mf = 0; mf < 8; ++mf) {
        #pragma unroll
        for (int nf = 0; nf < 4; ++nf) {
            const int n = n0 + wn * 64 + nf * 16 + colf;
            #pragma unroll
            for (int r = 0; r < 4; ++r) {
                const int row = m0 + wm * 128 + mf * 16 + rowf + r;
                float vv = acc[mf][nf][r];
                float sq = vv * vv;
                float other = __shfl_xor(sq, 1, 64);
                if (!(lane & 1)) {
                    float p = fminf((sq + other) * invs[row], 1.0f);
                    out[(size_t)row * DIM + (n >> 1)] = p;
                }
            }
        }
    }
}

extern "C" void kernel_launch(void* const* d_in, const int* in_sizes, int n_in,
                              void* d_out, int out_size, void* d_ws, size_t ws_size,
                              hipStream_t stream) {
    const float* x = (const float*)d_in[0];     // (8192,1,32,32) fp32
    const float* w = (const float*)d_in[1];     // (16,10,3) fp32
    float* out = (float*)d_out;                 // (8192,1,32,32) fp32

    char* ws = (char*)d_ws;
    float*     gates = (float*)(ws + WS_GATES);
    int*       iperm = (int*)(ws + WS_IPERM);
    float*     invs  = (float*)(ws + WS_INVS);
    _Float16*  Xh    = (_Float16*)(ws + WS_XH);
    _Float16*  Bil   = (_Float16*)(ws + WS_BIL);
    // Ucol scratch lives in d_out (4 MB of its 32 MB); consumed by transpose
    // before gemm overwrites every element of d_out.
    _Float16*  Ucol  = (_Float16*)d_out;

    prep_kernel<<<1, 1024, 0, stream>>>(w, gates, iperm);
    normcast_kernel<<<8192, 64, 0, stream>>>(x, Xh, invs);
    ubuild_kernel<<<1024, 256, 0, stream>>>(gates, iperm, Ucol);
    transpose_kernel<<<dim3(32, 16), 256, 0, stream>>>(Ucol, Bil);
    gemm_kernel<<<256, 512, 0, stream>>>(Xh, Bil, invs, out);
}